// Round 8
// baseline (485.789 us; speedup 1.0000x reference)
//
#include <hip/hip_runtime.h>

// ---------------------------------------------------------------------------
// 3-layer GCN. Factorized: tmp[n] = dinv[n]*(h[n]@W); agg[i]=dinv[i]*(tmp[i]+sum tmp[src])+b
// All fp32 (threshold ~1e-5 relative of max|out|~488; bf16 forbidden).
// GEMM v8: A in REGISTERS direct from global (broadcast-coalesced, 2-slot
// depth-2 prefetch) -- zero A-LDS traffic. W-only LDS (dbuf, b64 pair reads,
// conflict-free). Thread tile 8x4 (8x2 @C=64) -> grid 1563x2waves = 3/SIMD.
// Counted vmcnt(16) barrier keeps A prefetch in flight across chunk barrier.
// v7 lesson: 8x8 tile -> 1.5 waves/SIMD grid starvation + 1.5x LDS-pipe oversub.
// ---------------------------------------------------------------------------

// ---------------- CSR build ----------------

__global__ __launch_bounds__(256) void count_kernel(const int* __restrict__ dst,
                                                    int* __restrict__ cnt, int E) {
    int e = blockIdx.x * 256 + threadIdx.x;
    if (e < E) atomicAdd(&cnt[dst[e]], 1);
}

__global__ __launch_bounds__(256) void dinv_kernel(const int* __restrict__ cnt,
                                                   float* __restrict__ dinv, int M) {
    int i = blockIdx.x * 256 + threadIdx.x;
    if (i < M) dinv[i] = 1.0f / sqrtf((float)cnt[i] + 1.0f);  // +1: self-loop
}

__global__ __launch_bounds__(256) void scan1_kernel(const int* __restrict__ cnt,
                                                    int* __restrict__ loc,
                                                    int* __restrict__ bsum, int M) {
    __shared__ int sm[256];
    int t = threadIdx.x;
    int i = blockIdx.x * 256 + t;
    int v = (i < M) ? cnt[i] : 0;
    sm[t] = v;
    __syncthreads();
    for (int o = 1; o < 256; o <<= 1) {
        int add = (t >= o) ? sm[t - o] : 0;
        __syncthreads();
        sm[t] += add;
        __syncthreads();
    }
    if (i < M) loc[i] = sm[t] - v;
    if (t == 255) bsum[blockIdx.x] = sm[255];
}

__global__ __launch_bounds__(256) void scan2_kernel(int* __restrict__ bsum, int NB) {
    __shared__ int sm[256];
    int t = threadIdx.x;
    int v = (t < NB) ? bsum[t] : 0;
    sm[t] = v;
    __syncthreads();
    for (int o = 1; o < 256; o <<= 1) {
        int add = (t >= o) ? sm[t - o] : 0;
        __syncthreads();
        sm[t] += add;
        __syncthreads();
    }
    if (t < NB) bsum[t] = sm[t] - v;
}

__global__ __launch_bounds__(256) void place_kernel(const int* __restrict__ src,
                                                    const int* __restrict__ dst,
                                                    const int* __restrict__ loc,
                                                    const int* __restrict__ base,
                                                    int* __restrict__ fill,
                                                    int* __restrict__ srcs, int E) {
    int e = blockIdx.x * 256 + threadIdx.x;
    if (e >= E) return;
    int d = dst[e];
    int pos = loc[d] + base[d >> 8] + atomicAdd(&fill[d], 1);
    srcs[pos] = src[e];
}

// ---------------- GEMM v8 ----------------
// 128 threads = 2 waves. tx = t&31, ty = t>>5 (0..3). Block = 32 rows x C cols.
// Thread: 8 rows (row0 + 4i + ty) x CPT cols ({2tx,2tx+1} [+ {C/2+2tx,..}]).
// A: registers, 2-slot (aA/aB) depth-2 prefetch from global; W: LDS dbuf
// KB=16 staged via global_load_lds; chunk barrier = counted vmcnt(16).

__device__ __forceinline__ void gload_lds16(const float* g, float* l) {
    __builtin_amdgcn_global_load_lds((const __attribute__((address_space(1))) void*)g,
                                     (__attribute__((address_space(3))) void*)l,
                                     16, 0, 0);
}

template <int K, int C, int CPT>
__global__ __launch_bounds__(128) void gemm_v8(const float* __restrict__ A,
                                               const float* __restrict__ W,
                                               const float* __restrict__ dinv,
                                               float* __restrict__ out, int M) {
    constexpr int KB = 16;             // W k-chunk
    constexpr int NCH = K / KB;
    constexpr int NKQ = K / 4;         // float4 k-steps
    constexpr int WFL = KB * C;        // 2048 (C=128) / 1024 (C=64) floats
    constexpr int WR = WFL / (4 * 128);// W stage rounds: 4 / 2
    constexpr int NH = CPT / 2;        // column half-groups: 2 / 1

    __shared__ __align__(16) float Wb[2][WFL];

    const int t = threadIdx.x;
    const int tx = t & 31;
    const int ty = t >> 5;
    const int row0 = blockIdx.x * 32;

    int aoff[8];
#pragma unroll
    for (int i = 0; i < 8; ++i) {
        int r = row0 + 4 * i + ty;
        if (r >= M) r = M - 1;         // clamped rows never stored
        aoff[i] = r * K;
    }

    auto stageW = [&](int ch, int buf) {
        const int k0 = ch * KB;
#pragma unroll
        for (int rnd = 0; rnd < WR; ++rnd) {
            int L = rnd * 128 + t;
            gload_lds16(W + (size_t)k0 * C + L * 4, &Wb[buf][L * 4]);
        }
    };

    float4 aA[8], aB[8];
    auto loadA = [&](float4* dst, int kq) {
#pragma unroll
        for (int i = 0; i < 8; ++i)
            dst[i] = *(const float4*)(A + aoff[i] + kq * 4);
    };

    float acc[8][CPT];
#pragma unroll
    for (int i = 0; i < 8; ++i)
#pragma unroll
        for (int j = 0; j < CPT; ++j) acc[i][j] = 0.f;

    auto fmas = [&](const float4* s, const float* Wc, int ko) {
#pragma unroll
        for (int kk = 0; kk < 4; ++kk) {
            float2 w[NH];
#pragma unroll
            for (int h = 0; h < NH; ++h)
                w[h] = *(const float2*)&Wc[(ko + kk) * C + h * (C / 2) + 2 * tx];
#pragma unroll
            for (int i = 0; i < 8; ++i) {
                float av = (&s[i].x)[kk];
#pragma unroll
                for (int h = 0; h < NH; ++h) {
                    acc[i][h * 2 + 0] += av * w[h].x;
                    acc[i][h * 2 + 1] += av * w[h].y;
                }
            }
        }
    };

    // prologue: stage W chunk 0, load A kq 0,1; wait only for W (A stays in flight)
    stageW(0, 0);
    loadA(aA, 0);
    loadA(aB, 1);
    asm volatile("s_waitcnt vmcnt(16)" ::: "memory");
    __builtin_amdgcn_s_barrier();
    __builtin_amdgcn_sched_barrier(0);

    for (int ch = 0; ch < NCH; ++ch) {
        const bool pre = (ch + 1 < NCH);
        if (pre) stageW(ch + 1, (ch + 1) & 1);   // oldest VMEM this chunk
        const float* Wc = Wb[ch & 1];
#pragma unroll
        for (int q = 0; q < 2; ++q) {
            const int kq0 = ch * 4 + q * 2;
            fmas(aA, Wc, q * 8);
            { int kn = kq0 + 2; if (kn > NKQ - 1) kn = NKQ - 1; loadA(aA, kn); }
            fmas(aB, Wc, q * 8 + 4);
            { int kn = kq0 + 3; if (kn > NKQ - 1) kn = NKQ - 1; loadA(aB, kn); }
        }
        if (pre) {
            // wait for this chunk's W staging (oldest); leave the 16 newest
            // (next-chunk A prefetch) in flight across the barrier.
            asm volatile("s_waitcnt vmcnt(16)" ::: "memory");
            __builtin_amdgcn_s_barrier();
            __builtin_amdgcn_sched_barrier(0);
        }
    }

#pragma unroll
    for (int i = 0; i < 8; ++i) {
        int r = row0 + 4 * i + ty;
        if (r < M) {
            float dv = dinv[r];
#pragma unroll
            for (int h = 0; h < NH; ++h) {
                float2 v = make_float2(acc[i][h * 2 + 0] * dv,
                                       acc[i][h * 2 + 1] * dv);
                *(float2*)(out + (size_t)r * C + h * (C / 2) + 2 * tx) = v;
            }
        }
    }
}

// ---------------- Aggregation: out[i] = act(dinv[i]*(tmp[i] + sum tmp[src]) + b) ----------------
// Unroll x8 with index prefetch: 8 independent gathers in flight per thread.

template <int C, bool RELU>
__global__ __launch_bounds__(256) void agg_kernel(const float* __restrict__ tmp,
                                                  const int* __restrict__ srcs,
                                                  const int* __restrict__ cnt,
                                                  const int* __restrict__ loc,
                                                  const int* __restrict__ base,
                                                  const float* __restrict__ dinv,
                                                  const float* __restrict__ bias,
                                                  float* __restrict__ out, int M) {
    constexpr int TPN = C / 4;        // threads per node (float4 per thread)
    constexpr int NPB = 256 / TPN;    // nodes per block
    const int t = threadIdx.x;
    const int cq = t % TPN;
    const int node = blockIdx.x * NPB + t / TPN;
    if (node >= M) return;

    const float4* tmp4 = (const float4*)tmp;
    float4 acc = tmp4[(size_t)node * TPN + cq];   // self-loop term
    float4 acc2 = make_float4(0.f, 0.f, 0.f, 0.f);
    const int start = loc[node] + base[node >> 8];
    const int n = cnt[node];
    const int* sp = srcs + start;

    const int jn = n & ~7;
    int s[8];
    if (jn > 0) {
#pragma unroll
        for (int u = 0; u < 8; ++u) s[u] = sp[u];
    }
    for (int j = 0; j < jn; j += 8) {
        float4 v0 = tmp4[(size_t)s[0] * TPN + cq];
        float4 v1 = tmp4[(size_t)s[1] * TPN + cq];
        float4 v2 = tmp4[(size_t)s[2] * TPN + cq];
        float4 v3 = tmp4[(size_t)s[3] * TPN + cq];
        float4 v4 = tmp4[(size_t)s[4] * TPN + cq];
        float4 v5 = tmp4[(size_t)s[5] * TPN + cq];
        float4 v6 = tmp4[(size_t)s[6] * TPN + cq];
        float4 v7 = tmp4[(size_t)s[7] * TPN + cq];
        if (j + 8 < jn) {
#pragma unroll
            for (int u = 0; u < 8; ++u) s[u] = sp[j + 8 + u];
        }
        acc.x  += v0.x + v1.x;  acc.y  += v0.y + v1.y;
        acc.z  += v0.z + v1.z;  acc.w  += v0.w + v1.w;
        acc2.x += v2.x + v3.x;  acc2.y += v2.y + v3.y;
        acc2.z += v2.z + v3.z;  acc2.w += v2.w + v3.w;
        acc.x  += v4.x + v5.x;  acc.y  += v4.y + v5.y;
        acc.z  += v4.z + v5.z;  acc.w  += v4.w + v5.w;
        acc2.x += v6.x + v7.x;  acc2.y += v6.y + v7.y;
        acc2.z += v6.z + v7.z;  acc2.w += v6.w + v7.w;
    }
    for (int j = jn; j < n; ++j) {
        float4 v = tmp4[(size_t)sp[j] * TPN + cq];
        acc.x += v.x; acc.y += v.y; acc.z += v.z; acc.w += v.w;
    }
    acc.x += acc2.x; acc.y += acc2.y; acc.z += acc2.z; acc.w += acc2.w;

    float dv = dinv[node];
    float4 b = *(const float4*)(bias + cq * 4);
    float4 r;
    r.x = acc.x * dv + b.x;
    r.y = acc.y * dv + b.y;
    r.z = acc.z * dv + b.z;
    r.w = acc.w * dv + b.w;
    if (RELU) {
        r.x = fmaxf(r.x, 0.f); r.y = fmaxf(r.y, 0.f);
        r.z = fmaxf(r.z, 0.f); r.w = fmaxf(r.w, 0.f);
    }
    ((float4*)out)[(size_t)node * TPN + cq] = r;
}

// ---------------- launch ----------------

extern "C" void kernel_launch(void* const* d_in, const int* in_sizes, int n_in,
                              void* d_out, int out_size, void* d_ws, size_t ws_size,
                              hipStream_t stream) {
    const float* x  = (const float*)d_in[0];
    const int*   ei = (const int*)d_in[1];
    const float* W1 = (const float*)d_in[2];
    const float* b1 = (const float*)d_in[3];
    const float* W2 = (const float*)d_in[4];
    const float* b2 = (const float*)d_in[5];
    const float* W3 = (const float*)d_in[6];
    const float* b3 = (const float*)d_in[7];
    float* out = (float*)d_out;

    const int M = in_sizes[0] / 256;   // 50000 nodes
    const int E = in_sizes[1] / 2;     // 800000 edges
    const int NB = (M + 255) / 256;

    char* p = (char*)d_ws;
    auto alloc = [&](size_t bytes) {
        char* r = p;
        p += (bytes + 255) & ~(size_t)255;
        return r;
    };
    int*   cnt  = (int*)alloc((size_t)M * 4);
    int*   fill = (int*)alloc((size_t)M * 4);
    int*   loc  = (int*)alloc((size_t)M * 4);
    int*   base = (int*)alloc((size_t)NB * 4);
    float* dinv = (float*)alloc((size_t)M * 4);
    int*   srcs = (int*)alloc((size_t)E * 4);
    float* tmp  = (float*)alloc((size_t)M * 128 * 4);
    float* h    = (float*)alloc((size_t)M * 128 * 4);

    hipMemsetAsync(cnt, 0, (size_t)M * 4, stream);
    hipMemsetAsync(fill, 0, (size_t)M * 4, stream);

    const int* esrc = ei;
    const int* edst = ei + E;

    count_kernel<<<(E + 255) / 256, 256, 0, stream>>>(edst, cnt, E);
    dinv_kernel<<<(M + 255) / 256, 256, 0, stream>>>(cnt, dinv, M);
    scan1_kernel<<<NB, 256, 0, stream>>>(cnt, loc, base, M);
    scan2_kernel<<<1, 256, 0, stream>>>(base, NB);
    place_kernel<<<(E + 255) / 256, 256, 0, stream>>>(esrc, edst, loc, base, fill, srcs, E);

    const int ggrid = (M + 31) / 32;   // 1563 blocks, 2 waves each

    // layer 1: x[50000,256] @ W1[256,128] -> relu agg -> h
    gemm_v8<256, 128, 4><<<ggrid, 128, 0, stream>>>(x, W1, dinv, tmp, M);
    agg_kernel<128, true><<<(M + 7) / 8, 256, 0, stream>>>(tmp, srcs, cnt, loc, base, dinv, b1, h, M);

    // layer 2: h @ W2[128,128] -> relu agg -> h
    gemm_v8<128, 128, 4><<<ggrid, 128, 0, stream>>>(h, W2, dinv, tmp, M);
    agg_kernel<128, true><<<(M + 7) / 8, 256, 0, stream>>>(tmp, srcs, cnt, loc, base, dinv, b2, h, M);

    // layer 3: h @ W3[128,64] -> agg -> out
    gemm_v8<128, 64, 2><<<ggrid, 128, 0, stream>>>(h, W3, dinv, tmp, M);
    agg_kernel<64, false><<<(M + 15) / 16, 256, 0, stream>>>(tmp, srcs, cnt, loc, base, dinv, b3, out, M);
}

// Round 10
// 336.542 us; speedup vs baseline: 1.4435x; 1.4435x over previous
//
#include <hip/hip_runtime.h>

// ---------------------------------------------------------------------------
// 3-layer GCN. Factorized: tmp[n] = dinv[n]*(h[n]@W); agg[i]=dinv[i]*(tmp[i]+sum tmp[src])+b
// All fp32 (threshold ~1e-5 relative of max|out|~488; bf16 forbidden).
// GEMM: v2 (proven 71/72/40us) -- at the fp32 LDS-BW wall for this M.
// AGG: edge lists PADDED to multiples of 8 (dummy entries) -> branch-free
//   8-deep gather pipeline; dummy remapped PER LAYER to a zero row at the
//   same byte offset (M*128 floats) for both C=128 and C=64 strides.
//   (R9 bug: fixed dummy index M aliased live data under the C=64 stride.)
// ---------------------------------------------------------------------------

// ---------------- CSR build ----------------

__global__ __launch_bounds__(256) void count_kernel(const int* __restrict__ dst,
                                                    int* __restrict__ cnt, int E) {
    int e = blockIdx.x * 256 + threadIdx.x;
    if (e < E) atomicAdd(&cnt[dst[e]], 1);
}

// dinv from true degree; padded count for CSR layout
__global__ __launch_bounds__(256) void dinv_kernel(const int* __restrict__ cnt,
                                                   float* __restrict__ dinv,
                                                   int* __restrict__ pcnt, int M) {
    int i = blockIdx.x * 256 + threadIdx.x;
    if (i < M) {
        int c = cnt[i];
        dinv[i] = 1.0f / sqrtf((float)c + 1.0f);  // +1: self-loop
        pcnt[i] = (c + 7) & ~7;
    }
}

__global__ __launch_bounds__(256) void srcs_fill_kernel(int* __restrict__ srcs,
                                                        int val, int n) {
    int i = blockIdx.x * 256 + threadIdx.x;
    if (i < n) srcs[i] = val;
}

// block-local exclusive scan of pcnt -> loc; per-block total -> bsum
__global__ __launch_bounds__(256) void scan1_kernel(const int* __restrict__ pcnt,
                                                    int* __restrict__ loc,
                                                    int* __restrict__ bsum, int M) {
    __shared__ int sm[256];
    int t = threadIdx.x;
    int i = blockIdx.x * 256 + t;
    int v = (i < M) ? pcnt[i] : 0;
    sm[t] = v;
    __syncthreads();
    for (int o = 1; o < 256; o <<= 1) {
        int add = (t >= o) ? sm[t - o] : 0;
        __syncthreads();
        sm[t] += add;
        __syncthreads();
    }
    if (i < M) loc[i] = sm[t] - v;
    if (t == 255) bsum[blockIdx.x] = sm[255];
}

__global__ __launch_bounds__(256) void scan2_kernel(int* __restrict__ bsum, int NB) {
    __shared__ int sm[256];
    int t = threadIdx.x;
    int v = (t < NB) ? bsum[t] : 0;
    sm[t] = v;
    __syncthreads();
    for (int o = 1; o < 256; o <<= 1) {
        int add = (t >= o) ? sm[t - o] : 0;
        __syncthreads();
        sm[t] += add;
        __syncthreads();
    }
    if (t < NB) bsum[t] = sm[t] - v;
}

__global__ __launch_bounds__(256) void place_kernel(const int* __restrict__ src,
                                                    const int* __restrict__ dst,
                                                    const int* __restrict__ loc,
                                                    const int* __restrict__ base,
                                                    int* __restrict__ fill,
                                                    int* __restrict__ srcs, int E) {
    int e = blockIdx.x * 256 + threadIdx.x;
    if (e >= E) return;
    int d = dst[e];
    int pos = loc[d] + base[d >> 8] + atomicAdd(&fill[d], 1);
    srcs[pos] = src[e];
}

// ---------------- GEMM (v2, proven): out[m][c] = dinv[m] * sum_k A[m][k]*W[k][c] ----

template <int K, int C>
__global__ __launch_bounds__(256) void gemm_scale_kernel(const float* __restrict__ A,
                                                         const float* __restrict__ W,
                                                         const float* __restrict__ dinv,
                                                         float* __restrict__ out, int M) {
    constexpr int CT = C / 4;         // threads across columns (each owns 4 cols)
    constexpr int RT = 256 / CT;      // thread rows (each owns 4 rows)
    constexpr int TM = RT * 4;        // rows per block
    constexpr int KB = 32;            // k-chunk
    constexpr int AP = TM + 4;        // padded row stride (16B-aligned, breaks pow2)

    __shared__ __align__(16) float Ast[KB][AP];   // A tile, transposed: Ast[k][row]
    __shared__ __align__(16) float Bs[KB][C];

    const int t = threadIdx.x;
    const int tx = t % CT;
    const int ty = t / CT;
    const int row0 = blockIdx.x * TM;

    float acc[4][4];
#pragma unroll
    for (int i = 0; i < 4; i++)
#pragma unroll
        for (int j = 0; j < 4; j++) acc[i][j] = 0.f;

    constexpr int ALOADS = (TM * KB) / (256 * 4);  // float4 loads of A per thread
    constexpr int BLOADS = (KB * C) / (256 * 4);   // float4 loads of W per thread

    for (int k0 = 0; k0 < K; k0 += KB) {
#pragma unroll
        for (int l = 0; l < ALOADS; l++) {
            int idx = t + l * 256;
            int ar = idx >> 3;            // row within tile (8 float4 per 32-k row)
            int kq = (idx & 7) * 4;       // k offset
            int grow = row0 + ar;
            float4 v = make_float4(0.f, 0.f, 0.f, 0.f);
            if (grow < M) v = *(const float4*)(A + (size_t)grow * K + k0 + kq);
            Ast[kq + 0][ar] = v.x;
            Ast[kq + 1][ar] = v.y;
            Ast[kq + 2][ar] = v.z;
            Ast[kq + 3][ar] = v.w;
        }
#pragma unroll
        for (int l = 0; l < BLOADS; l++) {
            int idx = t + l * 256;
            int bk = idx / (C / 4);
            int bc = (idx % (C / 4)) * 4;
            *(float4*)(&Bs[bk][bc]) = *(const float4*)(W + (size_t)(k0 + bk) * C + bc);
        }
        __syncthreads();
#pragma unroll
        for (int k = 0; k < KB; k++) {
            float4 a = *(const float4*)(&Ast[k][ty * 4]);
            float4 b = *(const float4*)(&Bs[k][tx * 4]);
            acc[0][0] += a.x * b.x; acc[0][1] += a.x * b.y; acc[0][2] += a.x * b.z; acc[0][3] += a.x * b.w;
            acc[1][0] += a.y * b.x; acc[1][1] += a.y * b.y; acc[1][2] += a.y * b.z; acc[1][3] += a.y * b.w;
            acc[2][0] += a.z * b.x; acc[2][1] += a.z * b.y; acc[2][2] += a.z * b.z; acc[2][3] += a.z * b.w;
            acc[3][0] += a.w * b.x; acc[3][1] += a.w * b.y; acc[3][2] += a.w * b.z; acc[3][3] += a.w * b.w;
        }
        __syncthreads();
    }
#pragma unroll
    for (int i = 0; i < 4; i++) {
        int r = row0 + ty * 4 + i;
        if (r < M) {
            float dv = dinv[r];
            float4 v = make_float4(acc[i][0] * dv, acc[i][1] * dv, acc[i][2] * dv, acc[i][3] * dv);
            *(float4*)(out + (size_t)r * C + tx * 4) = v;
        }
    }
}

// ---------------- Aggregation: out[i] = act(dinv[i]*(tmp[i] + sum tmp[src]) + b) ----------------
// Padded edge lists (multiple of 8): branch-free 8-deep gather pipeline.
// Dummy entries hold value M in srcs; remapped here to DUMMY (per-layer index
// of the zeroed row under this layer's stride).

template <int C, bool RELU>
__global__ __launch_bounds__(256) void agg_kernel(const float* __restrict__ tmp,
                                                  const int* __restrict__ srcs,
                                                  const int* __restrict__ pcnt,
                                                  const int* __restrict__ loc,
                                                  const int* __restrict__ base,
                                                  const float* __restrict__ dinv,
                                                  const float* __restrict__ bias,
                                                  float* __restrict__ out,
                                                  int M, int DUMMY) {
    constexpr int TPN = C / 4;        // threads per node (float4 per thread)
    constexpr int NPB = 256 / TPN;    // nodes per block
    const int t = threadIdx.x;
    const int cq = t % TPN;
    const int node = blockIdx.x * NPB + t / TPN;
    if (node >= M) return;

    const float4* tmp4 = (const float4*)tmp;
    float4 acc = tmp4[(size_t)node * TPN + cq];   // self-loop term
    float4 acc2 = make_float4(0.f, 0.f, 0.f, 0.f);
    const int start = loc[node] + base[node >> 8];
    const int pn = pcnt[node];                    // multiple of 8
    const int* sp = srcs + start;                 // 32B-aligned (start % 8 == 0)

    auto remap = [&](int4& v) {
        v.x = v.x < M ? v.x : DUMMY;
        v.y = v.y < M ? v.y : DUMMY;
        v.z = v.z < M ? v.z : DUMMY;
        v.w = v.w < M ? v.w : DUMMY;
    };

    int4 ia, ib;
    if (pn > 0) {
        ia = *(const int4*)(sp); ib = *(const int4*)(sp + 4);
        remap(ia); remap(ib);
    }
    for (int j = 0; j < pn; j += 8) {
        float4 v0 = tmp4[(size_t)ia.x * TPN + cq];
        float4 v1 = tmp4[(size_t)ia.y * TPN + cq];
        float4 v2 = tmp4[(size_t)ia.z * TPN + cq];
        float4 v3 = tmp4[(size_t)ia.w * TPN + cq];
        float4 v4 = tmp4[(size_t)ib.x * TPN + cq];
        float4 v5 = tmp4[(size_t)ib.y * TPN + cq];
        float4 v6 = tmp4[(size_t)ib.z * TPN + cq];
        float4 v7 = tmp4[(size_t)ib.w * TPN + cq];
        if (j + 8 < pn) {
            ia = *(const int4*)(sp + j + 8);
            ib = *(const int4*)(sp + j + 12);
            remap(ia); remap(ib);
        }
        acc.x  += v0.x + v1.x;  acc.y  += v0.y + v1.y;
        acc.z  += v0.z + v1.z;  acc.w  += v0.w + v1.w;
        acc2.x += v2.x + v3.x;  acc2.y += v2.y + v3.y;
        acc2.z += v2.z + v3.z;  acc2.w += v2.w + v3.w;
        acc.x  += v4.x + v5.x;  acc.y  += v4.y + v5.y;
        acc.z  += v4.z + v5.z;  acc.w  += v4.w + v5.w;
        acc2.x += v6.x + v7.x;  acc2.y += v6.y + v7.y;
        acc2.z += v6.z + v7.z;  acc2.w += v6.w + v7.w;
    }
    acc.x += acc2.x; acc.y += acc2.y; acc.z += acc2.z; acc.w += acc2.w;

    float dv = dinv[node];
    float4 b = *(const float4*)(bias + cq * 4);
    float4 r;
    r.x = acc.x * dv + b.x;
    r.y = acc.y * dv + b.y;
    r.z = acc.z * dv + b.z;
    r.w = acc.w * dv + b.w;
    if (RELU) {
        r.x = fmaxf(r.x, 0.f); r.y = fmaxf(r.y, 0.f);
        r.z = fmaxf(r.z, 0.f); r.w = fmaxf(r.w, 0.f);
    }
    ((float4*)out)[(size_t)node * TPN + cq] = r;
}

// ---------------- launch ----------------

extern "C" void kernel_launch(void* const* d_in, const int* in_sizes, int n_in,
                              void* d_out, int out_size, void* d_ws, size_t ws_size,
                              hipStream_t stream) {
    const float* x  = (const float*)d_in[0];
    const int*   ei = (const int*)d_in[1];
    const float* W1 = (const float*)d_in[2];
    const float* b1 = (const float*)d_in[3];
    const float* W2 = (const float*)d_in[4];
    const float* b2 = (const float*)d_in[5];
    const float* W3 = (const float*)d_in[6];
    const float* b3 = (const float*)d_in[7];
    float* out = (float*)d_out;

    const int M = in_sizes[0] / 256;   // 50000 nodes
    const int E = in_sizes[1] / 2;     // 800000 edges
    const int NB = (M + 255) / 256;
    const int SRCN = E + 8 * M;        // padded srcs upper bound

    char* p = (char*)d_ws;
    auto alloc = [&](size_t bytes) {
        char* r = p;
        p += (bytes + 255) & ~(size_t)255;
        return r;
    };
    int*   cnt  = (int*)alloc((size_t)M * 4);
    int*   pcnt = (int*)alloc((size_t)M * 4);
    int*   fill = (int*)alloc((size_t)M * 4);
    int*   loc  = (int*)alloc((size_t)M * 4);
    int*   base = (int*)alloc((size_t)NB * 4);
    float* dinv = (float*)alloc((size_t)M * 4);
    int*   srcs = (int*)alloc((size_t)SRCN * 4);
    float* tmp  = (float*)alloc((size_t)(M + 1) * 128 * 4);  // +1: zero dummy row
    float* h    = (float*)alloc((size_t)M * 128 * 4);

    hipMemsetAsync(cnt, 0, (size_t)M * 4, stream);
    hipMemsetAsync(fill, 0, (size_t)M * 4, stream);
    // zero dummy region at float offset M*128: row M under stride 128 (C=128
    // layers) AND row 2M under stride 64 (C=64 layer) -> same bytes.
    hipMemsetAsync(tmp + (size_t)M * 128, 0, 128 * 4, stream);

    const int* esrc = ei;
    const int* edst = ei + E;

    count_kernel<<<(E + 255) / 256, 256, 0, stream>>>(edst, cnt, E);
    dinv_kernel<<<(M + 255) / 256, 256, 0, stream>>>(cnt, dinv, pcnt, M);
    scan1_kernel<<<NB, 256, 0, stream>>>(pcnt, loc, base, M);
    scan2_kernel<<<1, 256, 0, stream>>>(base, NB);
    srcs_fill_kernel<<<(SRCN + 255) / 256, 256, 0, stream>>>(srcs, M, SRCN);
    place_kernel<<<(E + 255) / 256, 256, 0, stream>>>(esrc, edst, loc, base, fill, srcs, E);

    // layer 1: x[50000,256] @ W1[256,128] -> relu agg -> h
    gemm_scale_kernel<256, 128><<<(M + 31) / 32, 256, 0, stream>>>(x, W1, dinv, tmp, M);
    agg_kernel<128, true><<<(M + 7) / 8, 256, 0, stream>>>(tmp, srcs, pcnt, loc, base, dinv, b1, h, M, M);

    // layer 2: h @ W2[128,128] -> relu agg -> h
    gemm_scale_kernel<128, 128><<<(M + 31) / 32, 256, 0, stream>>>(h, W2, dinv, tmp, M);
    agg_kernel<128, true><<<(M + 7) / 8, 256, 0, stream>>>(tmp, srcs, pcnt, loc, base, dinv, b2, h, M, M);

    // layer 3: h @ W3[128,64] -> agg -> out  (dummy row index 2M under stride 64)
    gemm_scale_kernel<128, 64><<<(M + 63) / 64, 256, 0, stream>>>(h, W3, dinv, tmp, M);
    agg_kernel<64, false><<<(M + 15) / 16, 256, 0, stream>>>(tmp, srcs, pcnt, loc, base, dinv, b3, out, M, 2 * M);
}